// Round 1
// baseline (1515.365 us; speedup 1.0000x reference)
//
#include <hip/hip_runtime.h>
#include <hip/hip_bf16.h>

#define T_TOK 4096
#define H_DIM 4096
#define I_DIM 2048
#define N_EXP 8
#define TOPK  2
#define NPAIR (T_TOK*TOPK)          // 8192
#define BM    128
#define BK    32
#define MAXT  (NPAIR/BM + N_EXP)    // 72

typedef __attribute__((ext_vector_type(8))) short  bf16x8;
typedef __attribute__((ext_vector_type(4))) float  f32x4v;

__device__ __forceinline__ short f2bf(float f) {
    __hip_bfloat16 h = __float2bfloat16(f);
    return __builtin_bit_cast(short, h);
}

__device__ __forceinline__ bf16x8 pack8(f32x4v a, f32x4v b) {
    bf16x8 r;
    r[0]=f2bf(a[0]); r[1]=f2bf(a[1]); r[2]=f2bf(a[2]); r[3]=f2bf(a[3]);
    r[4]=f2bf(b[0]); r[5]=f2bf(b[1]); r[6]=f2bf(b[2]); r[7]=f2bf(b[3]);
    return r;
}

// ---------------- routing: deterministic permute + tile descriptors ----------------
__global__ void route_kernel(const int* __restrict__ ids, const float* __restrict__ wts,
                             int* __restrict__ pair_token, float* __restrict__ pair_w,
                             int* __restrict__ tile_expert, int* __restrict__ tile_row0,
                             int* __restrict__ tile_rows)
{
    __shared__ int scn[256][N_EXP];
    const int tid = threadIdx.x;
    const int PPT = NPAIR / 256;           // 32
    const int base = tid * PPT;

    int c[N_EXP], orig[N_EXP];
    #pragma unroll
    for (int e = 0; e < N_EXP; ++e) c[e] = 0;
    for (int p = 0; p < PPT; ++p) c[ids[base + p]]++;
    #pragma unroll
    for (int e = 0; e < N_EXP; ++e) { orig[e] = c[e]; scn[tid][e] = c[e]; }
    __syncthreads();

    // Hillis-Steele inclusive scan over 256 threads, 8 experts wide
    for (int off = 1; off < 256; off <<= 1) {
        int add[N_EXP];
        #pragma unroll
        for (int e = 0; e < N_EXP; ++e) add[e] = (tid >= off) ? scn[tid - off][e] : 0;
        __syncthreads();
        #pragma unroll
        for (int e = 0; e < N_EXP; ++e) { c[e] += add[e]; scn[tid][e] = c[e]; }
        __syncthreads();
    }

    // segment starts
    int segs[N_EXP + 1];
    {
        int run = 0;
        #pragma unroll
        for (int e = 0; e < N_EXP; ++e) { segs[e] = run; run += scn[255][e]; }
        segs[N_EXP] = run;
    }
    // per-thread scatter cursor (exclusive prefix)
    int pos[N_EXP];
    #pragma unroll
    for (int e = 0; e < N_EXP; ++e) pos[e] = segs[e] + c[e] - orig[e];

    for (int p = 0; p < PPT; ++p) {
        int pp = base + p;
        int e = ids[pp];
        int q = pos[e]++;
        pair_token[q] = pp / TOPK;
        pair_w[q]     = wts[pp];
    }

    if (tid == 0) {
        int t = 0;
        for (int e = 0; e < N_EXP; ++e) {
            int s = segs[e], en = segs[e + 1];
            for (int r = s; r < en; r += BM) {
                tile_expert[t] = e;
                tile_row0[t]   = r;
                tile_rows[t]   = min(BM, en - r);
                ++t;
            }
        }
        for (; t < MAXT; ++t) { tile_expert[t] = 0; tile_row0[t] = 0; tile_rows[t] = 0; }
    }
}

// ---------------- GEMM1: h = silu(x@wi0^T) * (x@wi1^T) * pair_w  (bf16 out) ----------------
__global__ __launch_bounds__(256, 3) void gemm1_kernel(
    const float* __restrict__ X,        // [T][H]
    const float* __restrict__ Wi0,      // [E][I][H]
    const float* __restrict__ Wi1,      // [E][I][H]
    const int* __restrict__ pair_token, const float* __restrict__ pair_w,
    const int* __restrict__ tile_expert, const int* __restrict__ tile_row0,
    const int* __restrict__ tile_rows,
    short* __restrict__ Hbuf)           // [NPAIR][I] bf16 bits
{
    const int tile = blockIdx.x;
    const int rows = tile_rows[tile];
    if (rows == 0) return;
    const int e    = tile_expert[tile];
    const int row0 = tile_row0[tile];
    const int n0   = blockIdx.y * 64;   // over I

    __shared__ short sA [BM][BK + 8];
    __shared__ short sB0[64][BK + 8];
    __shared__ short sB1[64][BK + 8];
    __shared__ int   sTok[BM];
    __shared__ float sPw [BM];

    const int tid = threadIdx.x;
    if (tid < BM) {
        int tr = min(tid, rows - 1);
        sTok[tid] = pair_token[row0 + tr];
        sPw[tid]  = (tid < rows) ? pair_w[row0 + tid] : 0.f;
    }
    __syncthreads();

    // staging maps
    const int arow  = tid >> 1;          // 0..127
    const int ahalf = tid & 1;           // cols 16*ahalf..+16
    const int brow  = tid >> 2;          // 0..63
    const int bq    = tid & 3;           // cols 8*bq..+8

    const float* aptr  = X + (size_t)sTok[arow] * H_DIM + ahalf * 16;
    const size_t wboff = ((size_t)e * I_DIM + (n0 + brow)) * H_DIM + bq * 8;
    const float* b0ptr = Wi0 + wboff;
    const float* b1ptr = Wi1 + wboff;

    f32x4v ra[4], rb0[2], rb1[2];
    f32x4v accg[4][2], accu[4][2];
    #pragma unroll
    for (int mf = 0; mf < 4; ++mf)
        #pragma unroll
        for (int nf = 0; nf < 2; ++nf) {
            accg[mf][nf] = (f32x4v)0.f;
            accu[mf][nf] = (f32x4v)0.f;
        }

    const int lane = tid & 63;
    const int wid  = tid >> 6;
    const int wr   = wid >> 1;   // 0..1 : 64-row half
    const int wc   = wid & 1;    // 0..1 : 32-col half
    const int frow = lane & 15;
    const int fk   = (lane >> 4) * 8;

    // prologue load k=0
    {
        const float* a = aptr;
        ra[0] = *(const f32x4v*)(a);      ra[1] = *(const f32x4v*)(a + 4);
        ra[2] = *(const f32x4v*)(a + 8);  ra[3] = *(const f32x4v*)(a + 12);
        rb0[0] = *(const f32x4v*)(b0ptr); rb0[1] = *(const f32x4v*)(b0ptr + 4);
        rb1[0] = *(const f32x4v*)(b1ptr); rb1[1] = *(const f32x4v*)(b1ptr + 4);
    }

    const int KT = H_DIM / BK;   // 128
    for (int kt = 0; kt < KT; ++kt) {
        __syncthreads();
        *(bf16x8*)&sA [arow][ahalf * 16]     = pack8(ra[0], ra[1]);
        *(bf16x8*)&sA [arow][ahalf * 16 + 8] = pack8(ra[2], ra[3]);
        *(bf16x8*)&sB0[brow][bq * 8]         = pack8(rb0[0], rb0[1]);
        *(bf16x8*)&sB1[brow][bq * 8]         = pack8(rb1[0], rb1[1]);
        __syncthreads();

        if (kt + 1 < KT) {
            const int k = (kt + 1) * BK;
            ra[0] = *(const f32x4v*)(aptr + k);      ra[1] = *(const f32x4v*)(aptr + k + 4);
            ra[2] = *(const f32x4v*)(aptr + k + 8);  ra[3] = *(const f32x4v*)(aptr + k + 12);
            rb0[0] = *(const f32x4v*)(b0ptr + k);    rb0[1] = *(const f32x4v*)(b0ptr + k + 4);
            rb1[0] = *(const f32x4v*)(b1ptr + k);    rb1[1] = *(const f32x4v*)(b1ptr + k + 4);
        }

        bf16x8 af[4], b0f[2], b1f[2];
        #pragma unroll
        for (int mf = 0; mf < 4; ++mf)
            af[mf] = *(const bf16x8*)&sA[wr * 64 + mf * 16 + frow][fk];
        #pragma unroll
        for (int nf = 0; nf < 2; ++nf) {
            b0f[nf] = *(const bf16x8*)&sB0[wc * 32 + nf * 16 + frow][fk];
            b1f[nf] = *(const bf16x8*)&sB1[wc * 32 + nf * 16 + frow][fk];
        }
        #pragma unroll
        for (int mf = 0; mf < 4; ++mf)
            #pragma unroll
            for (int nf = 0; nf < 2; ++nf) {
                accg[mf][nf] = __builtin_amdgcn_mfma_f32_16x16x32_bf16(af[mf], b0f[nf], accg[mf][nf], 0, 0, 0);
                accu[mf][nf] = __builtin_amdgcn_mfma_f32_16x16x32_bf16(af[mf], b1f[nf], accu[mf][nf], 0, 0, 0);
            }
    }

    // epilogue: silu(g)*u*w -> bf16
    const int r4 = (lane >> 4) * 4;
    #pragma unroll
    for (int mf = 0; mf < 4; ++mf)
        #pragma unroll
        for (int nf = 0; nf < 2; ++nf)
            #pragma unroll
            for (int j = 0; j < 4; ++j) {
                int rr = wr * 64 + mf * 16 + r4 + j;
                if (rr < rows) {
                    float g = accg[mf][nf][j];
                    float u = accu[mf][nf][j];
                    float sig = 1.f / (1.f + __expf(-g));
                    float v = g * sig * u * sPw[rr];
                    int col = n0 + wc * 32 + nf * 16 + (lane & 15);
                    Hbuf[(size_t)(row0 + rr) * I_DIM + col] = f2bf(v);
                }
            }
}

// ---------------- GEMM2: out[token] += h @ wo^T ----------------
__global__ __launch_bounds__(256, 3) void gemm2_kernel(
    const short* __restrict__ Hbuf,     // [NPAIR][I] bf16 bits
    const float* __restrict__ Wo,       // [E][H][I]
    const int* __restrict__ pair_token,
    const int* __restrict__ tile_expert, const int* __restrict__ tile_row0,
    const int* __restrict__ tile_rows,
    float* __restrict__ out)            // [T][H]
{
    const int tile = blockIdx.x;
    const int rows = tile_rows[tile];
    if (rows == 0) return;
    const int e    = tile_expert[tile];
    const int row0 = tile_row0[tile];
    const int n0   = blockIdx.y * 64;   // over H

    __shared__ short sA[BM][BK + 8];
    __shared__ short sB[64][BK + 8];
    __shared__ int   sTok[BM];

    const int tid = threadIdx.x;
    if (tid < BM) {
        int tr = min(tid, rows - 1);
        sTok[tid] = pair_token[row0 + tr];
    }
    __syncthreads();

    const int arow  = tid >> 1;
    const int ahalf = tid & 1;
    const int brow  = tid >> 2;
    const int bq    = tid & 3;

    const short* aptr = Hbuf + (size_t)(row0 + min(arow, rows - 1)) * I_DIM + ahalf * 16;
    const float* bptr = Wo + ((size_t)e * H_DIM + (n0 + brow)) * I_DIM + bq * 8;

    bf16x8 raA[2];
    f32x4v rb[2];
    f32x4v acc[4][2];
    #pragma unroll
    for (int mf = 0; mf < 4; ++mf)
        #pragma unroll
        for (int nf = 0; nf < 2; ++nf) acc[mf][nf] = (f32x4v)0.f;

    const int lane = tid & 63;
    const int wid  = tid >> 6;
    const int wr   = wid >> 1;
    const int wc   = wid & 1;
    const int frow = lane & 15;
    const int fk   = (lane >> 4) * 8;

    raA[0] = *(const bf16x8*)(aptr);
    raA[1] = *(const bf16x8*)(aptr + 8);
    rb[0]  = *(const f32x4v*)(bptr);
    rb[1]  = *(const f32x4v*)(bptr + 4);

    const int KT = I_DIM / BK;   // 64
    for (int kt = 0; kt < KT; ++kt) {
        __syncthreads();
        *(bf16x8*)&sA[arow][ahalf * 16]     = raA[0];
        *(bf16x8*)&sA[arow][ahalf * 16 + 8] = raA[1];
        *(bf16x8*)&sB[brow][bq * 8]         = pack8(rb[0], rb[1]);
        __syncthreads();

        if (kt + 1 < KT) {
            const int k = (kt + 1) * BK;
            raA[0] = *(const bf16x8*)(aptr + k);
            raA[1] = *(const bf16x8*)(aptr + k + 8);
            rb[0]  = *(const f32x4v*)(bptr + k);
            rb[1]  = *(const f32x4v*)(bptr + k + 4);
        }

        bf16x8 af[4], bf[2];
        #pragma unroll
        for (int mf = 0; mf < 4; ++mf)
            af[mf] = *(const bf16x8*)&sA[wr * 64 + mf * 16 + frow][fk];
        #pragma unroll
        for (int nf = 0; nf < 2; ++nf)
            bf[nf] = *(const bf16x8*)&sB[wc * 32 + nf * 16 + frow][fk];
        #pragma unroll
        for (int mf = 0; mf < 4; ++mf)
            #pragma unroll
            for (int nf = 0; nf < 2; ++nf)
                acc[mf][nf] = __builtin_amdgcn_mfma_f32_16x16x32_bf16(af[mf], bf[nf], acc[mf][nf], 0, 0, 0);
    }

    const int r4 = (lane >> 4) * 4;
    #pragma unroll
    for (int mf = 0; mf < 4; ++mf)
        #pragma unroll
        for (int nf = 0; nf < 2; ++nf)
            #pragma unroll
            for (int j = 0; j < 4; ++j) {
                int rr = wr * 64 + mf * 16 + r4 + j;
                if (rr < rows) {
                    int col = n0 + wc * 32 + nf * 16 + (lane & 15);
                    atomicAdd(out + (size_t)sTok[rr] * H_DIM + col, acc[mf][nf][j]);
                }
            }
}

// ---------------- launch ----------------
extern "C" void kernel_launch(void* const* d_in, const int* in_sizes, int n_in,
                              void* d_out, int out_size, void* d_ws, size_t ws_size,
                              hipStream_t stream)
{
    (void)in_sizes; (void)n_in; (void)ws_size;
    const float* X     = (const float*)d_in[0];
    const float* topw  = (const float*)d_in[1];
    const int*   topid = (const int*)d_in[2];
    const float* Wi0   = (const float*)d_in[3];
    const float* Wi1   = (const float*)d_in[4];
    const float* Wo    = (const float*)d_in[5];
    float* out = (float*)d_out;

    char* ws = (char*)d_ws;
    int*   pair_token  = (int*)ws;                         // NPAIR ints
    float* pair_w      = (float*)(ws + NPAIR * 4);         // NPAIR floats
    int*   tile_expert = (int*)(ws + NPAIR * 8);
    int*   tile_row0   = tile_expert + MAXT;
    int*   tile_rows   = tile_row0 + MAXT;
    short* Hbuf        = (short*)(ws + (1 << 20));         // NPAIR*I_DIM bf16 = 33.6MB

    hipMemsetAsync(d_out, 0, (size_t)out_size * sizeof(float), stream);

    route_kernel<<<1, 256, 0, stream>>>(topid, topw, pair_token, pair_w,
                                        tile_expert, tile_row0, tile_rows);

    gemm1_kernel<<<dim3(MAXT, I_DIM / 64), 256, 0, stream>>>(
        X, Wi0, Wi1, pair_token, pair_w, tile_expert, tile_row0, tile_rows, Hbuf);

    gemm2_kernel<<<dim3(MAXT, H_DIM / 64), 256, 0, stream>>>(
        Hbuf, Wo, pair_token, tile_expert, tile_row0, tile_rows, out);
}

// Round 2
// 1172.771 us; speedup vs baseline: 1.2921x; 1.2921x over previous
//
#include <hip/hip_runtime.h>
#include <hip/hip_bf16.h>

#define T_TOK 4096
#define H_DIM 4096
#define I_DIM 2048
#define N_EXP 8
#define TOPK  2
#define NPAIR (T_TOK*TOPK)          // 8192
#define BM    128
#define BK    32
#define MAXT  (NPAIR/BM + N_EXP)    // 72

typedef __attribute__((ext_vector_type(8))) short  bf16x8;
typedef __attribute__((ext_vector_type(4))) float  f32x4v;

__device__ __forceinline__ short f2bf(float f) {
    __hip_bfloat16 h = __float2bfloat16(f);
    return __builtin_bit_cast(short, h);
}

__device__ __forceinline__ bf16x8 pack8(f32x4v a, f32x4v b) {
    bf16x8 r;
    r[0]=f2bf(a[0]); r[1]=f2bf(a[1]); r[2]=f2bf(a[2]); r[3]=f2bf(a[3]);
    r[4]=f2bf(b[0]); r[5]=f2bf(b[1]); r[6]=f2bf(b[2]); r[7]=f2bf(b[3]);
    return r;
}

// ---------------- X -> bf16 (into d_out scratch region) ----------------
__global__ void cvt_kernel(const float* __restrict__ X, short* __restrict__ Xbf) {
    const int i = (blockIdx.x * 256 + threadIdx.x) * 8;
    f32x4v a = *(const f32x4v*)(X + i);
    f32x4v b = *(const f32x4v*)(X + i + 4);
    *(bf16x8*)(Xbf + i) = pack8(a, b);
}

// ---------------- routing: deterministic permute + tile descriptors ----------------
__global__ void route_kernel(const int* __restrict__ ids, const float* __restrict__ wts,
                             int* __restrict__ pair_token, float* __restrict__ pair_w,
                             int* __restrict__ tile_expert, int* __restrict__ tile_row0,
                             int* __restrict__ tile_rows)
{
    __shared__ int scn[256][N_EXP];
    const int tid = threadIdx.x;
    const int PPT = NPAIR / 256;           // 32
    const int base = tid * PPT;

    int c[N_EXP], orig[N_EXP];
    #pragma unroll
    for (int e = 0; e < N_EXP; ++e) c[e] = 0;
    for (int p = 0; p < PPT; ++p) c[ids[base + p]]++;
    #pragma unroll
    for (int e = 0; e < N_EXP; ++e) { orig[e] = c[e]; scn[tid][e] = c[e]; }
    __syncthreads();

    for (int off = 1; off < 256; off <<= 1) {
        int add[N_EXP];
        #pragma unroll
        for (int e = 0; e < N_EXP; ++e) add[e] = (tid >= off) ? scn[tid - off][e] : 0;
        __syncthreads();
        #pragma unroll
        for (int e = 0; e < N_EXP; ++e) { c[e] += add[e]; scn[tid][e] = c[e]; }
        __syncthreads();
    }

    int segs[N_EXP + 1];
    {
        int run = 0;
        #pragma unroll
        for (int e = 0; e < N_EXP; ++e) { segs[e] = run; run += scn[255][e]; }
        segs[N_EXP] = run;
    }
    int pos[N_EXP];
    #pragma unroll
    for (int e = 0; e < N_EXP; ++e) pos[e] = segs[e] + c[e] - orig[e];

    for (int p = 0; p < PPT; ++p) {
        int pp = base + p;
        int e = ids[pp];
        int q = pos[e]++;
        pair_token[q] = pp / TOPK;
        pair_w[q]     = wts[pp];
    }

    if (tid == 0) {
        int t = 0;
        for (int e = 0; e < N_EXP; ++e) {
            int s = segs[e], en = segs[e + 1];
            for (int r = s; r < en; r += BM) {
                tile_expert[t] = e;
                tile_row0[t]   = r;
                tile_rows[t]   = min(BM, en - r);
                ++t;
            }
        }
        for (; t < MAXT; ++t) { tile_expert[t] = 0; tile_row0[t] = 0; tile_rows[t] = 0; }
    }
}

// ---------------- GEMM1: h = silu(x@wi0^T)*(x@wi1^T)*pair_w, tile 128x128 both mats ----------------
__global__ __launch_bounds__(256, 2) void gemm1_kernel(
    const short* __restrict__ Xbf,      // [T][H] bf16
    const float* __restrict__ Wi0,      // [E][I][H]
    const float* __restrict__ Wi1,      // [E][I][H]
    const int* __restrict__ pair_token, const float* __restrict__ pair_w,
    const int* __restrict__ tile_expert, const int* __restrict__ tile_row0,
    const int* __restrict__ tile_rows,
    short* __restrict__ Hbuf)           // [NPAIR][I] bf16
{
    const int tile = blockIdx.x;
    const int rows = tile_rows[tile];
    if (rows == 0) return;
    const int e    = tile_expert[tile];
    const int row0 = tile_row0[tile];
    const int n0   = blockIdx.y * 128;   // over I

    __shared__ short sA [BM][BK + 8];
    __shared__ short sB0[128][BK + 8];
    __shared__ short sB1[128][BK + 8];
    __shared__ int   sTok[BM];
    __shared__ float sPw [BM];

    const int tid = threadIdx.x;
    if (tid < BM) {
        int tr = min(tid, rows - 1);
        sTok[tid] = pair_token[row0 + tr];
        sPw[tid]  = (tid < rows) ? pair_w[row0 + tid] : 0.f;
    }
    __syncthreads();

    // staging map: slot = tid, row = tid>>1 (0..127), half = tid&1 -> 16 cols
    const int srow  = tid >> 1;
    const int shalf = tid & 1;

    const short* aptr  = Xbf + (size_t)sTok[srow] * H_DIM + shalf * 16;
    const size_t wboff = ((size_t)e * I_DIM + (n0 + srow)) * H_DIM + shalf * 16;
    const float* b0ptr = Wi0 + wboff;
    const float* b1ptr = Wi1 + wboff;

    bf16x8 ra[2];
    f32x4v rb0[4], rb1[4];
    f32x4v accg[4][4], accu[4][4];
    #pragma unroll
    for (int mf = 0; mf < 4; ++mf)
        #pragma unroll
        for (int nf = 0; nf < 4; ++nf) { accg[mf][nf] = (f32x4v)0.f; accu[mf][nf] = (f32x4v)0.f; }

    const int lane = tid & 63;
    const int wid  = tid >> 6;
    const int wr   = wid >> 1;   // M half (64 rows)
    const int wc   = wid & 1;    // N half (64 cols)
    const int frow = lane & 15;
    const int fk   = (lane >> 4) * 8;

    // prologue: load kt=0
    ra[0] = *(const bf16x8*)(aptr);
    ra[1] = *(const bf16x8*)(aptr + 8);
    #pragma unroll
    for (int i = 0; i < 4; ++i) { rb0[i] = *(const f32x4v*)(b0ptr + i * 4); rb1[i] = *(const f32x4v*)(b1ptr + i * 4); }

    const int KT = H_DIM / BK;   // 128
    for (int kt = 0; kt < KT; ++kt) {
        __syncthreads();
        *(bf16x8*)&sA [srow][shalf * 16]     = ra[0];
        *(bf16x8*)&sA [srow][shalf * 16 + 8] = ra[1];
        *(bf16x8*)&sB0[srow][shalf * 16]     = pack8(rb0[0], rb0[1]);
        *(bf16x8*)&sB0[srow][shalf * 16 + 8] = pack8(rb0[2], rb0[3]);
        *(bf16x8*)&sB1[srow][shalf * 16]     = pack8(rb1[0], rb1[1]);
        *(bf16x8*)&sB1[srow][shalf * 16 + 8] = pack8(rb1[2], rb1[3]);
        __syncthreads();

        if (kt + 1 < KT) {
            const int k = (kt + 1) * BK;
            ra[0] = *(const bf16x8*)(aptr + k);
            ra[1] = *(const bf16x8*)(aptr + k + 8);
            #pragma unroll
            for (int i = 0; i < 4; ++i) { rb0[i] = *(const f32x4v*)(b0ptr + k + i * 4); rb1[i] = *(const f32x4v*)(b1ptr + k + i * 4); }
        }

        bf16x8 af[4];
        #pragma unroll
        for (int mf = 0; mf < 4; ++mf)
            af[mf] = *(const bf16x8*)&sA[wr * 64 + mf * 16 + frow][fk];
        #pragma unroll
        for (int nf = 0; nf < 4; ++nf) {
            bf16x8 b0f = *(const bf16x8*)&sB0[wc * 64 + nf * 16 + frow][fk];
            bf16x8 b1f = *(const bf16x8*)&sB1[wc * 64 + nf * 16 + frow][fk];
            #pragma unroll
            for (int mf = 0; mf < 4; ++mf) {
                accg[mf][nf] = __builtin_amdgcn_mfma_f32_16x16x32_bf16(af[mf], b0f, accg[mf][nf], 0, 0, 0);
                accu[mf][nf] = __builtin_amdgcn_mfma_f32_16x16x32_bf16(af[mf], b1f, accu[mf][nf], 0, 0, 0);
            }
        }
    }

    const int r4 = (lane >> 4) * 4;
    #pragma unroll
    for (int mf = 0; mf < 4; ++mf)
        #pragma unroll
        for (int nf = 0; nf < 4; ++nf)
            #pragma unroll
            for (int j = 0; j < 4; ++j) {
                int rr = wr * 64 + mf * 16 + r4 + j;
                if (rr < rows) {
                    float g = accg[mf][nf][j];
                    float u = accu[mf][nf][j];
                    float sig = 1.f / (1.f + __expf(-g));
                    float v = g * sig * u * sPw[rr];
                    int col = n0 + wc * 64 + nf * 16 + (lane & 15);
                    Hbuf[(size_t)(row0 + rr) * I_DIM + col] = f2bf(v);
                }
            }
}

// ---------------- GEMM2: out[token] += h @ wo^T, tile 128x256 ----------------
__global__ __launch_bounds__(256, 2) void gemm2_kernel(
    const short* __restrict__ Hbuf,     // [NPAIR][I] bf16
    const float* __restrict__ Wo,       // [E][H][I]
    const int* __restrict__ pair_token,
    const int* __restrict__ tile_expert, const int* __restrict__ tile_row0,
    const int* __restrict__ tile_rows,
    float* __restrict__ out)            // [T][H]
{
    const int tile = blockIdx.x;
    const int rows = tile_rows[tile];
    if (rows == 0) return;
    const int e    = tile_expert[tile];
    const int row0 = tile_row0[tile];
    const int n0   = blockIdx.y * 256;   // over H

    __shared__ short sA[BM][BK + 8];
    __shared__ short sB[256][BK + 8];
    __shared__ int   sTok[BM];

    const int tid = threadIdx.x;
    if (tid < BM) sTok[tid] = pair_token[row0 + min(tid, rows - 1)];
    __syncthreads();

    const int srow  = tid >> 1;
    const int shalf = tid & 1;

    const short* aptr = Hbuf + (size_t)(row0 + min(srow, rows - 1)) * I_DIM + shalf * 16;
    // B slots: this thread handles Wo rows (n0+srow) and (n0+srow+128), same 16-col half
    const float* bptrA = Wo + ((size_t)e * H_DIM + (n0 + srow))       * I_DIM + shalf * 16;
    const float* bptrB = Wo + ((size_t)e * H_DIM + (n0 + srow + 128)) * I_DIM + shalf * 16;

    bf16x8 ra[2];
    f32x4v rbA[4], rbB[4];
    f32x4v acc[4][8];
    #pragma unroll
    for (int mf = 0; mf < 4; ++mf)
        #pragma unroll
        for (int nf = 0; nf < 8; ++nf) acc[mf][nf] = (f32x4v)0.f;

    const int lane = tid & 63;
    const int wid  = tid >> 6;
    const int wr   = wid >> 1;   // M half (64 rows)
    const int wc   = wid & 1;    // N half (128 cols)
    const int frow = lane & 15;
    const int fk   = (lane >> 4) * 8;

    ra[0] = *(const bf16x8*)(aptr);
    ra[1] = *(const bf16x8*)(aptr + 8);
    #pragma unroll
    for (int i = 0; i < 4; ++i) { rbA[i] = *(const f32x4v*)(bptrA + i * 4); rbB[i] = *(const f32x4v*)(bptrB + i * 4); }

    const int KT = I_DIM / BK;   // 64
    for (int kt = 0; kt < KT; ++kt) {
        __syncthreads();
        *(bf16x8*)&sA[srow][shalf * 16]           = ra[0];
        *(bf16x8*)&sA[srow][shalf * 16 + 8]       = ra[1];
        *(bf16x8*)&sB[srow][shalf * 16]           = pack8(rbA[0], rbA[1]);
        *(bf16x8*)&sB[srow][shalf * 16 + 8]       = pack8(rbA[2], rbA[3]);
        *(bf16x8*)&sB[srow + 128][shalf * 16]     = pack8(rbB[0], rbB[1]);
        *(bf16x8*)&sB[srow + 128][shalf * 16 + 8] = pack8(rbB[2], rbB[3]);
        __syncthreads();

        if (kt + 1 < KT) {
            const int k = (kt + 1) * BK;
            ra[0] = *(const bf16x8*)(aptr + k);
            ra[1] = *(const bf16x8*)(aptr + k + 8);
            #pragma unroll
            for (int i = 0; i < 4; ++i) { rbA[i] = *(const f32x4v*)(bptrA + k + i * 4); rbB[i] = *(const f32x4v*)(bptrB + k + i * 4); }
        }

        bf16x8 af[4];
        #pragma unroll
        for (int mf = 0; mf < 4; ++mf)
            af[mf] = *(const bf16x8*)&sA[wr * 64 + mf * 16 + frow][fk];
        #pragma unroll
        for (int nf = 0; nf < 8; ++nf) {
            bf16x8 bfv = *(const bf16x8*)&sB[wc * 128 + nf * 16 + frow][fk];
            #pragma unroll
            for (int mf = 0; mf < 4; ++mf)
                acc[mf][nf] = __builtin_amdgcn_mfma_f32_16x16x32_bf16(af[mf], bfv, acc[mf][nf], 0, 0, 0);
        }
    }

    const int r4 = (lane >> 4) * 4;
    #pragma unroll
    for (int mf = 0; mf < 4; ++mf)
        #pragma unroll
        for (int nf = 0; nf < 8; ++nf)
            #pragma unroll
            for (int j = 0; j < 4; ++j) {
                int rr = wr * 64 + mf * 16 + r4 + j;
                if (rr < rows) {
                    int col = n0 + wc * 128 + nf * 16 + (lane & 15);
                    atomicAdd(out + (size_t)sTok[rr] * H_DIM + col, acc[mf][nf][j]);
                }
            }
}

// ---------------- launch ----------------
extern "C" void kernel_launch(void* const* d_in, const int* in_sizes, int n_in,
                              void* d_out, int out_size, void* d_ws, size_t ws_size,
                              hipStream_t stream)
{
    (void)in_sizes; (void)n_in; (void)ws_size;
    const float* X     = (const float*)d_in[0];
    const float* topw  = (const float*)d_in[1];
    const int*   topid = (const int*)d_in[2];
    const float* Wi0   = (const float*)d_in[3];
    const float* Wi1   = (const float*)d_in[4];
    const float* Wo    = (const float*)d_in[5];
    float* out = (float*)d_out;

    char* ws = (char*)d_ws;
    int*   pair_token  = (int*)ws;                         // NPAIR ints
    float* pair_w      = (float*)(ws + NPAIR * 4);         // NPAIR floats
    int*   tile_expert = (int*)(ws + NPAIR * 8);
    int*   tile_row0   = tile_expert + MAXT;
    int*   tile_rows   = tile_row0 + MAXT;
    short* Hbuf        = (short*)(ws + (1 << 20));         // NPAIR*I_DIM bf16 = 33.6MB

    short* Xbf = (short*)d_out;   // 33.6MB scratch inside 67MB out buffer (freed by memset below)

    cvt_kernel<<<T_TOK * H_DIM / (256 * 8), 256, 0, stream>>>(X, Xbf);
    route_kernel<<<1, 256, 0, stream>>>(topid, topw, pair_token, pair_w,
                                        tile_expert, tile_row0, tile_rows);

    gemm1_kernel<<<dim3(MAXT, I_DIM / 128), 256, 0, stream>>>(
        Xbf, Wi0, Wi1, pair_token, pair_w, tile_expert, tile_row0, tile_rows, Hbuf);

    // Xbf no longer needed -> reclaim d_out for the real output
    hipMemsetAsync(d_out, 0, (size_t)out_size * sizeof(float), stream);

    gemm2_kernel<<<dim3(MAXT, H_DIM / 256), 256, 0, stream>>>(
        Hbuf, Wo, pair_token, tile_expert, tile_row0, tile_rows, out);
}

// Round 3
// 1134.274 us; speedup vs baseline: 1.3360x; 1.0339x over previous
//
#include <hip/hip_runtime.h>
#include <hip/hip_bf16.h>

#define T_TOK 4096
#define H_DIM 4096
#define I_DIM 2048
#define N_EXP 8
#define TOPK  2
#define NPAIR (T_TOK*TOPK)          // 8192
#define BM    128                   // gemm2 M-tile
#define BK    32
#define MAXT  (NPAIR/BM + N_EXP)    // 72
#define BM1   256                   // gemm1 M-tile
#define BN1   128
#define BK1   64
#define MAXT1 (NPAIR/BM1 + N_EXP)   // 40

typedef __attribute__((ext_vector_type(8))) short  bf16x8;
typedef __attribute__((ext_vector_type(4))) float  f32x4v;

__device__ __forceinline__ short f2bf(float f) {
    __hip_bfloat16 h = __float2bfloat16(f);
    return __builtin_bit_cast(short, h);
}

__device__ __forceinline__ bf16x8 pack8(f32x4v a, f32x4v b) {
    bf16x8 r;
    r[0]=f2bf(a[0]); r[1]=f2bf(a[1]); r[2]=f2bf(a[2]); r[3]=f2bf(a[3]);
    r[4]=f2bf(b[0]); r[5]=f2bf(b[1]); r[6]=f2bf(b[2]); r[7]=f2bf(b[3]);
    return r;
}

__device__ __forceinline__ void load_lds16(const short* g, short* l) {
    __builtin_amdgcn_global_load_lds(
        (const __attribute__((address_space(1))) void*)g,
        (__attribute__((address_space(3))) void*)l, 16, 0, 0);
}

// ---------------- X -> bf16 (into d_out scratch region) ----------------
__global__ void cvt_kernel(const float* __restrict__ X, short* __restrict__ Xbf) {
    const int i = (blockIdx.x * 256 + threadIdx.x) * 8;
    f32x4v a = *(const f32x4v*)(X + i);
    f32x4v b = *(const f32x4v*)(X + i + 4);
    *(bf16x8*)(Xbf + i) = pack8(a, b);
}

// ---------------- routing: deterministic permute + tile descriptors ----------------
__global__ void route_kernel(const int* __restrict__ ids, const float* __restrict__ wts,
                             int* __restrict__ pair_token, float* __restrict__ pair_w,
                             int* __restrict__ tile_expert, int* __restrict__ tile_row0,
                             int* __restrict__ tile_rows,
                             int* __restrict__ t1_expert, int* __restrict__ t1_row0,
                             int* __restrict__ t1_rows)
{
    __shared__ int scn[256][N_EXP];
    const int tid = threadIdx.x;
    const int PPT = NPAIR / 256;           // 32
    const int base = tid * PPT;

    int c[N_EXP], orig[N_EXP];
    #pragma unroll
    for (int e = 0; e < N_EXP; ++e) c[e] = 0;
    for (int p = 0; p < PPT; ++p) c[ids[base + p]]++;
    #pragma unroll
    for (int e = 0; e < N_EXP; ++e) { orig[e] = c[e]; scn[tid][e] = c[e]; }
    __syncthreads();

    for (int off = 1; off < 256; off <<= 1) {
        int add[N_EXP];
        #pragma unroll
        for (int e = 0; e < N_EXP; ++e) add[e] = (tid >= off) ? scn[tid - off][e] : 0;
        __syncthreads();
        #pragma unroll
        for (int e = 0; e < N_EXP; ++e) { c[e] += add[e]; scn[tid][e] = c[e]; }
        __syncthreads();
    }

    int segs[N_EXP + 1];
    {
        int run = 0;
        #pragma unroll
        for (int e = 0; e < N_EXP; ++e) { segs[e] = run; run += scn[255][e]; }
        segs[N_EXP] = run;
    }
    int pos[N_EXP];
    #pragma unroll
    for (int e = 0; e < N_EXP; ++e) pos[e] = segs[e] + c[e] - orig[e];

    for (int p = 0; p < PPT; ++p) {
        int pp = base + p;
        int e = ids[pp];
        int q = pos[e]++;
        pair_token[q] = pp / TOPK;
        pair_w[q]     = wts[pp];
    }

    if (tid == 0) {
        int t = 0;
        for (int e = 0; e < N_EXP; ++e) {
            int s = segs[e], en = segs[e + 1];
            for (int r = s; r < en; r += BM) {
                tile_expert[t] = e; tile_row0[t] = r; tile_rows[t] = min(BM, en - r); ++t;
            }
        }
        for (; t < MAXT; ++t) { tile_expert[t] = 0; tile_row0[t] = 0; tile_rows[t] = 0; }

        t = 0;
        for (int e = 0; e < N_EXP; ++e) {
            int s = segs[e], en = segs[e + 1];
            for (int r = s; r < en; r += BM1) {
                t1_expert[t] = e; t1_row0[t] = r; t1_rows[t] = min(BM1, en - r); ++t;
            }
        }
        for (; t < MAXT1; ++t) { t1_expert[t] = 0; t1_row0[t] = 0; t1_rows[t] = 0; }
    }
}

// ---------------- GEMM1: 256x128 tile, dbuf LDS, global_load_lds A, write-late ----------------
__global__ __launch_bounds__(512, 2) void gemm1_kernel(
    const short* __restrict__ Xbf,      // [T][H] bf16
    const float* __restrict__ Wi0,      // [E][I][H]
    const float* __restrict__ Wi1,      // [E][I][H]
    const int* __restrict__ pair_token, const float* __restrict__ pair_w,
    const int* __restrict__ t1_expert, const int* __restrict__ t1_row0,
    const int* __restrict__ t1_rows,
    short* __restrict__ Hbuf)           // [NPAIR][I] bf16
{
    const int tile = blockIdx.x;
    const int rows = t1_rows[tile];
    if (rows == 0) return;
    const int e    = t1_expert[tile];
    const int row0 = t1_row0[tile];
    const int n0   = blockIdx.y * BN1;

    // A: linear layout (global_load_lds), source pre-swizzled: chunk' = chunk ^ (row&7)
    __shared__ short sA [2][BM1][BK1];        // 64 KB
    __shared__ short sB0[2][BN1][BK1 + 8];    // 36 KB
    __shared__ short sB1[2][BN1][BK1 + 8];    // 36 KB
    __shared__ int   sTok[BM1];
    __shared__ float sPw [BM1];

    const int tid  = threadIdx.x;
    const int lane = tid & 63;
    const int w    = tid >> 6;          // wave 0..7

    if (tid < BM1) {
        int tr = min(tid, rows - 1);
        sTok[tid] = pair_token[row0 + tr];
        sPw[tid]  = (tid < rows) ? pair_w[row0 + tid] : 0.f;
    }
    __syncthreads();

    // ---- per-lane A source pointers (4 issues/wave fill 256 rows x 64 cols) ----
    const short* aSrc[4];
    #pragma unroll
    for (int i = 0; i < 4; ++i) {
        int r = w * 32 + i * 8 + (lane >> 3);
        int j = lane & 7;
        aSrc[i] = Xbf + (size_t)sTok[r] * H_DIM + ((j ^ (r & 7)) * 8);
    }

    // ---- B staging map: thread -> row tid>>2 (0..127), quarter tid&3 (16 cols) ----
    const int brow = tid >> 2;
    const int bq   = tid & 3;
    const size_t wboff = ((size_t)e * I_DIM + (n0 + brow)) * H_DIM + bq * 16;
    const float* b0p = Wi0 + wboff;
    const float* b1p = Wi1 + wboff;

    // ---- wave output tile: 64x64 (dual mat) ----
    const int wr   = w >> 1;            // 0..3
    const int wc   = w & 1;             // 0..1
    const int frow = lane & 15;
    const int fsel = lane >> 4;         // 0..3

    f32x4v accg[4][4], accu[4][4];
    #pragma unroll
    for (int mf = 0; mf < 4; ++mf)
        #pragma unroll
        for (int nf = 0; nf < 4; ++nf) { accg[mf][nf] = (f32x4v)0.f; accu[mf][nf] = (f32x4v)0.f; }

    f32x4v rb0[4], rb1[4];

    // ---- prologue: stage kt=0 into buffer 0 ----
    #pragma unroll
    for (int i = 0; i < 4; ++i)
        load_lds16(aSrc[i], &sA[0][w * 32 + i * 8][0]);
    #pragma unroll
    for (int i = 0; i < 4; ++i) { rb0[i] = *(const f32x4v*)(b0p + i * 4); rb1[i] = *(const f32x4v*)(b1p + i * 4); }
    {
        short* d0 = &sB0[0][brow][bq * 16];
        *(bf16x8*)d0       = pack8(rb0[0], rb0[1]);
        *(bf16x8*)(d0 + 8) = pack8(rb0[2], rb0[3]);
        short* d1 = &sB1[0][brow][bq * 16];
        *(bf16x8*)d1       = pack8(rb1[0], rb1[1]);
        *(bf16x8*)(d1 + 8) = pack8(rb1[2], rb1[3]);
    }
    __syncthreads();

    const int KT = H_DIM / BK1;   // 64
    for (int kt = 0; kt < KT; ++kt) {
        const int cur = kt & 1, nxt = cur ^ 1;

        // issue-early: next tile's loads (A direct-to-LDS, B to regs)
        if (kt + 1 < KT) {
            #pragma unroll
            for (int i = 0; i < 4; ++i)
                load_lds16(aSrc[i] + (kt + 1) * BK1, &sA[nxt][w * 32 + i * 8][0]);
            const float* p0 = b0p + (kt + 1) * BK1;
            const float* p1 = b1p + (kt + 1) * BK1;
            #pragma unroll
            for (int i = 0; i < 4; ++i) { rb0[i] = *(const f32x4v*)(p0 + i * 4); rb1[i] = *(const f32x4v*)(p1 + i * 4); }
        }

        // compute on cur
        #pragma unroll
        for (int h = 0; h < 2; ++h) {
            bf16x8 af[4], b0f[4], b1f[4];
            #pragma unroll
            for (int mf = 0; mf < 4; ++mf) {
                int ar = wr * 64 + mf * 16 + frow;
                int c  = (h * 4 + fsel) ^ (ar & 7);
                af[mf] = *(const bf16x8*)((const char*)&sA[cur][0][0] + ar * (BK1 * 2) + c * 16);
            }
            #pragma unroll
            for (int nf = 0; nf < 4; ++nf) {
                int br = wc * 64 + nf * 16 + frow;
                b0f[nf] = *(const bf16x8*)&sB0[cur][br][h * 32 + fsel * 8];
                b1f[nf] = *(const bf16x8*)&sB1[cur][br][h * 32 + fsel * 8];
            }
            #pragma unroll
            for (int nf = 0; nf < 4; ++nf)
                #pragma unroll
                for (int mf = 0; mf < 4; ++mf) {
                    accg[mf][nf] = __builtin_amdgcn_mfma_f32_16x16x32_bf16(af[mf], b0f[nf], accg[mf][nf], 0, 0, 0);
                    accu[mf][nf] = __builtin_amdgcn_mfma_f32_16x16x32_bf16(af[mf], b1f[nf], accu[mf][nf], 0, 0, 0);
                }
        }

        // write-late: B regs -> LDS nxt (vmcnt wait lands here, hidden under MFMA above)
        if (kt + 1 < KT) {
            short* d0 = &sB0[nxt][brow][bq * 16];
            *(bf16x8*)d0       = pack8(rb0[0], rb0[1]);
            *(bf16x8*)(d0 + 8) = pack8(rb0[2], rb0[3]);
            short* d1 = &sB1[nxt][brow][bq * 16];
            *(bf16x8*)d1       = pack8(rb1[0], rb1[1]);
            *(bf16x8*)(d1 + 8) = pack8(rb1[2], rb1[3]);
        }
        __syncthreads();   // also drains A global_load_lds for nxt
    }

    // ---- epilogue: silu(g)*u*pw -> bf16 ----
    const int r4 = fsel * 4;
    #pragma unroll
    for (int mf = 0; mf < 4; ++mf)
        #pragma unroll
        for (int nf = 0; nf < 4; ++nf)
            #pragma unroll
            for (int j = 0; j < 4; ++j) {
                int rr = wr * 64 + mf * 16 + r4 + j;
                if (rr < rows) {
                    float g = accg[mf][nf][j];
                    float u = accu[mf][nf][j];
                    float sig = 1.f / (1.f + __expf(-g));
                    float v = g * sig * u * sPw[rr];
                    int col = n0 + wc * 64 + nf * 16 + frow;
                    Hbuf[(size_t)(row0 + rr) * I_DIM + col] = f2bf(v);
                }
            }
}

// ---------------- GEMM2: out[token] += h @ wo^T, tile 128x256 (unchanged) ----------------
__global__ __launch_bounds__(256, 2) void gemm2_kernel(
    const short* __restrict__ Hbuf,     // [NPAIR][I] bf16
    const float* __restrict__ Wo,       // [E][H][I]
    const int* __restrict__ pair_token,
    const int* __restrict__ tile_expert, const int* __restrict__ tile_row0,
    const int* __restrict__ tile_rows,
    float* __restrict__ out)            // [T][H]
{
    const int tile = blockIdx.x;
    const int rows = tile_rows[tile];
    if (rows == 0) return;
    const int e    = tile_expert[tile];
    const int row0 = tile_row0[tile];
    const int n0   = blockIdx.y * 256;   // over H

    __shared__ short sA[BM][BK + 8];
    __shared__ short sB[256][BK + 8];
    __shared__ int   sTok[BM];

    const int tid = threadIdx.x;
    if (tid < BM) sTok[tid] = pair_token[row0 + min(tid, rows - 1)];
    __syncthreads();

    const int srow  = tid >> 1;
    const int shalf = tid & 1;

    const short* aptr = Hbuf + (size_t)(row0 + min(srow, rows - 1)) * I_DIM + shalf * 16;
    const float* bptrA = Wo + ((size_t)e * H_DIM + (n0 + srow))       * I_DIM + shalf * 16;
    const float* bptrB = Wo + ((size_t)e * H_DIM + (n0 + srow + 128)) * I_DIM + shalf * 16;

    bf16x8 ra[2];
    f32x4v rbA[4], rbB[4];
    f32x4v acc[4][8];
    #pragma unroll
    for (int mf = 0; mf < 4; ++mf)
        #pragma unroll
        for (int nf = 0; nf < 8; ++nf) acc[mf][nf] = (f32x4v)0.f;

    const int lane = tid & 63;
    const int wid  = tid >> 6;
    const int wr   = wid >> 1;
    const int wc   = wid & 1;
    const int frow = lane & 15;
    const int fk   = (lane >> 4) * 8;

    ra[0] = *(const bf16x8*)(aptr);
    ra[1] = *(const bf16x8*)(aptr + 8);
    #pragma unroll
    for (int i = 0; i < 4; ++i) { rbA[i] = *(const f32x4v*)(bptrA + i * 4); rbB[i] = *(const f32x4v*)(bptrB + i * 4); }

    const int KT = I_DIM / BK;   // 64
    for (int kt = 0; kt < KT; ++kt) {
        __syncthreads();
        *(bf16x8*)&sA[srow][shalf * 16]           = ra[0];
        *(bf16x8*)&sA[srow][shalf * 16 + 8]       = ra[1];
        *(bf16x8*)&sB[srow][shalf * 16]           = pack8(rbA[0], rbA[1]);
        *(bf16x8*)&sB[srow][shalf * 16 + 8]       = pack8(rbA[2], rbA[3]);
        *(bf16x8*)&sB[srow + 128][shalf * 16]     = pack8(rbB[0], rbB[1]);
        *(bf16x8*)&sB[srow + 128][shalf * 16 + 8] = pack8(rbB[2], rbB[3]);
        __syncthreads();

        if (kt + 1 < KT) {
            const int k = (kt + 1) * BK;
            ra[0] = *(const bf16x8*)(aptr + k);
            ra[1] = *(const bf16x8*)(aptr + k + 8);
            #pragma unroll
            for (int i = 0; i < 4; ++i) { rbA[i] = *(const f32x4v*)(bptrA + k + i * 4); rbB[i] = *(const f32x4v*)(bptrB + k + i * 4); }
        }

        bf16x8 af[4];
        #pragma unroll
        for (int mf = 0; mf < 4; ++mf)
            af[mf] = *(const bf16x8*)&sA[wr * 64 + mf * 16 + frow][fk];
        #pragma unroll
        for (int nf = 0; nf < 8; ++nf) {
            bf16x8 bfv = *(const bf16x8*)&sB[wc * 128 + nf * 16 + frow][fk];
            #pragma unroll
            for (int mf = 0; mf < 4; ++mf)
                acc[mf][nf] = __builtin_amdgcn_mfma_f32_16x16x32_bf16(af[mf], bfv, acc[mf][nf], 0, 0, 0);
        }
    }

    const int r4 = (lane >> 4) * 4;
    #pragma unroll
    for (int mf = 0; mf < 4; ++mf)
        #pragma unroll
        for (int nf = 0; nf < 8; ++nf)
            #pragma unroll
            for (int j = 0; j < 4; ++j) {
                int rr = wr * 64 + mf * 16 + r4 + j;
                if (rr < rows) {
                    int col = n0 + wc * 128 + nf * 16 + (lane & 15);
                    atomicAdd(out + (size_t)sTok[rr] * H_DIM + col, acc[mf][nf][j]);
                }
            }
}

// ---------------- launch ----------------
extern "C" void kernel_launch(void* const* d_in, const int* in_sizes, int n_in,
                              void* d_out, int out_size, void* d_ws, size_t ws_size,
                              hipStream_t stream)
{
    (void)in_sizes; (void)n_in; (void)ws_size;
    const float* X     = (const float*)d_in[0];
    const float* topw  = (const float*)d_in[1];
    const int*   topid = (const int*)d_in[2];
    const float* Wi0   = (const float*)d_in[3];
    const float* Wi1   = (const float*)d_in[4];
    const float* Wo    = (const float*)d_in[5];
    float* out = (float*)d_out;

    char* ws = (char*)d_ws;
    int*   pair_token  = (int*)ws;                         // NPAIR ints
    float* pair_w      = (float*)(ws + NPAIR * 4);         // NPAIR floats
    int*   tile_expert = (int*)(ws + NPAIR * 8);
    int*   tile_row0   = tile_expert + MAXT;
    int*   tile_rows   = tile_row0 + MAXT;
    int*   t1_expert   = tile_rows + MAXT;
    int*   t1_row0     = t1_expert + MAXT1;
    int*   t1_rows     = t1_row0 + MAXT1;
    short* Hbuf        = (short*)(ws + (1 << 20));         // NPAIR*I_DIM bf16 = 33.6MB

    short* Xbf = (short*)d_out;   // 33.6MB scratch inside 67MB out buffer (reclaimed below)

    cvt_kernel<<<T_TOK * H_DIM / (256 * 8), 256, 0, stream>>>(X, Xbf);
    route_kernel<<<1, 256, 0, stream>>>(topid, topw, pair_token, pair_w,
                                        tile_expert, tile_row0, tile_rows,
                                        t1_expert, t1_row0, t1_rows);

    gemm1_kernel<<<dim3(MAXT1, I_DIM / BN1), 512, 0, stream>>>(
        Xbf, Wi0, Wi1, pair_token, pair_w, t1_expert, t1_row0, t1_rows, Hbuf);

    // Xbf no longer needed -> reclaim d_out for the real output
    hipMemsetAsync(d_out, 0, (size_t)out_size * sizeof(float), stream);

    gemm2_kernel<<<dim3(MAXT, H_DIM / 256), 256, 0, stream>>>(
        Hbuf, Wo, pair_token, tile_expert, tile_row0, tile_rows, out);
}